// Round 20
// baseline (313.481 us; speedup 1.0000x reference)
//
#include <hip/hip_runtime.h>

#define HDIM 768
#define BM 64                 // rows per block
#define NCHUNK 24             // K chunks of 32
#define CHALF 24576           // halves per Wt chunk (768 cols * 32 k)
#define A_STRIDE 1552         // bytes per A row in LDS (768*2 + 16 pad)

typedef _Float16 f16x8 __attribute__((ext_vector_type(8)));
typedef _Float16 f16x4 __attribute__((ext_vector_type(4)));
typedef _Float16 f16x2 __attribute__((ext_vector_type(2)));
typedef float f32x4 __attribute__((ext_vector_type(4)));
typedef float f32x16 __attribute__((ext_vector_type(16)));

#define MFMA32(A, B, C) __builtin_amdgcn_mfma_f32_32x32x16_f16(A, B, C, 0, 0, 0)

// ---- LDS layout (bytes), dynamic: 109824 ----
#define LDS_A     0            // A resident: [64][1552B] = 99328
#define LDS_BIAS  99328        // 768 f32
#define LDS_V     102400       // 768 f32
#define LDS_SRED  105472       // [8][64] f32 = 2048 (4KB reserved)
#define LDS_E     109568       // 64 f32
#define LDS_TOTAL 109824

// ---- workspace layout (bytes) ----
#define WS_WT    0             // 768*768*2 = 1179648 (fp16 W, chunked [kc32][col][32k], linear)
#define WS_Z     1179648       // 4 (+pad) [absorbs the benign tail B-prefetch OOB reads]
#define WS_PART  1179712       // 2048*768*4 = 6291456
#define WS_PART2 7471168       // 16*768*4 = 49152
#define WS_NEED  (WS_PART2 + 49152)

__device__ __forceinline__ float tanh_fast(float z) {
    float e2 = __expf(2.0f * z);
    return 1.0f - 2.0f / (e2 + 1.0f);   // inf-safe at both extremes
}

__device__ __forceinline__ f16x8 cvt8(f32x4 x0, f32x4 x1) {
    f16x8 f;
    f[0] = (_Float16)x0[0]; f[1] = (_Float16)x0[1];
    f[2] = (_Float16)x0[2]; f[3] = (_Float16)x0[3];
    f[4] = (_Float16)x1[0]; f[5] = (_Float16)x1[1];
    f[6] = (_Float16)x1[2]; f[7] = (_Float16)x1[3];
    return f;
}

// ---------------- kernel 1: W -> fp16 chunks [kc32][col][32k] (linear); zero Z + acc ----------------
__global__ __launch_bounds__(1024) void prep_kernel(
    const float* __restrict__ W, _Float16* __restrict__ Wt,
    float* __restrict__ Z, float* __restrict__ accbuf) {
    int idx = blockIdx.x * 1024 + threadIdx.x;      // 73728 groups: 768 c x 24 kc x 4 q
    if (idx < 73728) {
        int c  = idx / 96;
        int r  = idx - c * 96;
        int kc = r >> 2;
        int q  = r & 3;
        const float* src = W + c * HDIM + kc * 32 + q * 8;
        f16x8 v = cvt8(*(const f32x4*)src, *(const f32x4*)(src + 4));
        *(f16x8*)(Wt + (size_t)kc * CHALF + c * 32 + q * 8) = v;
    }
    if (idx < HDIM) accbuf[idx] = 0.0f;
    if (idx == 0) *Z = 0.0f;
}

// ---------------- kernel 2: fused GEMM + tanh + v-dot + exp + weighted sum ----------------
// r20 = r15 structure re-geometried onto mfma_f32_32x32x16_f16: same 16B A + 16B B per
// lane feeds 2x the FLOPs -> per chunk/CU: DS halves (770->~385cy), MFMA 931->775cy,
// VALU shrinks; L2-B unchanged. r12-r19 showed the pipes serialize (wall = sum of pipes,
// immune to scheduling), so shrinking non-MFMA pipe demand is the remaining lever.
// 512 threads (8 waves, 2/SIMD -> 256-reg budget; occupancy proven irrelevant r13/r18).
// Wave = 3 col-tiles of 32 x 2 row-tiles of 32; acc 2x3 f32x16 = 96 AGPR.
// Fragment maps: A/B row|col = lane&31, k = (lane>>5)*8+e; C/D col = lane&31,
// row = (reg&3)+8*(reg>>2)+4*(lane>>5) [m74/m101].
__global__ __launch_bounds__(512, 2) void score_fused_kernel(
    const float* __restrict__ h, const _Float16* __restrict__ Wt,
    const float* __restrict__ bias, const float* __restrict__ vvec,
    float* __restrict__ part, float* __restrict__ accbuf,
    float* __restrict__ Z, int use_part) {

    extern __shared__ char smem[];
    float* bias_s = (float*)(smem + LDS_BIAS);
    float* v_s    = (float*)(smem + LDS_V);
    float* s_red  = (float*)(smem + LDS_SRED);
    float* e_lds  = (float*)(smem + LDS_E);

    const int tid  = threadIdx.x;
    const int wave = tid >> 6;       // 0..7 = col-group (96 cols each)
    const int lane = tid & 63;
    const int l31  = lane & 31;
    const int lhi  = lane >> 5;      // 0..1 (k-half within fragment)
    const int row0 = blockIdx.x * BM;

    for (int j = tid; j < HDIM; j += 512) { bias_s[j] = bias[j]; v_s[j] = vvec[j]; }

    // ---- prologue: stage ENTIRE A tile (64 x 768 fp32 -> fp16), coalesced ----
    #pragma unroll
    for (int i = 0; i < 24; ++i) {
        int flat = i * 512 + tid;           // 0..12287 = 64 rows x 192 f32x4
        int r  = flat / 192;
        int c4 = flat - r * 192;
        f32x4 x = __builtin_nontemporal_load(
            (const f32x4*)(h + (size_t)(row0 + r) * HDIM + c4 * 4));
        f16x4 v;
        v[0] = (_Float16)x[0]; v[1] = (_Float16)x[1];
        v[2] = (_Float16)x[2]; v[3] = (_Float16)x[3];
        *(f16x4*)(smem + LDS_A + r * A_STRIDE + c4 * 8) = v;
    }

    // B prefetch ping set = chunk 0 (ct,ks): offsets ct*1024 + ks*16 halves
    const _Float16* wtp = Wt + (wave * 96 + l31) * 32 + lhi * 8;
    f16x8 pA0 = *(const f16x8*)(wtp);            // ct0 ks0
    f16x8 pA1 = *(const f16x8*)(wtp + 16);       // ct0 ks1
    f16x8 pA2 = *(const f16x8*)(wtp + 1024);     // ct1 ks0
    f16x8 pA3 = *(const f16x8*)(wtp + 1040);     // ct1 ks1
    f16x8 pA4 = *(const f16x8*)(wtp + 2048);     // ct2 ks0
    f16x8 pA5 = *(const f16x8*)(wtp + 2064);     // ct2 ks1
    f16x8 pB0, pB1, pB2, pB3, pB4, pB5;

    __syncthreads();   // the only pre-epilogue barrier: A tile + bias/v visible

    f32x16 acc[2][3];
    #pragma unroll
    for (int rt = 0; rt < 2; ++rt)
        #pragma unroll
        for (int ct = 0; ct < 3; ++ct)
            #pragma unroll
            for (int e = 0; e < 16; ++e)
                acc[rt][ct][e] = 0.f;

    const char* aBase = smem + LDS_A + l31 * A_STRIDE + lhi * 16;

// compute chunk KC (ABSOLUTE index; pointers never advance) from B set C0..C5
// (C0=ct0ks0, C1=ct0ks1, C2=ct1ks0, C3=ct1ks1, C4=ct2ks0, C5=ct2ks1); prefetch
// chunk KC+1 into N0..N5. A frags: (rt,ks) at rt*32*A_STRIDE + KC*64 + ks*32 bytes.
// Tail: KC=23 prefetches chunk 24 -> 48KB past Wt into Z/part (mapped, unused).
#define CHUNK(KC, C0, C1, C2, C3, C4, C5, N0, N1, N2, N3, N4, N5)                        \
    {                                                                                    \
        const _Float16* wn = wtp + (size_t)((KC) + 1) * CHALF;                           \
        N0 = *(const f16x8*)(wn);                                                        \
        N1 = *(const f16x8*)(wn + 16);                                                   \
        N2 = *(const f16x8*)(wn + 1024);                                                 \
        N3 = *(const f16x8*)(wn + 1040);                                                 \
        N4 = *(const f16x8*)(wn + 2048);                                                 \
        N5 = *(const f16x8*)(wn + 2064);                                                 \
        const char* ab = aBase + (KC) * 64;                                              \
        f16x8 a00 = *(const f16x8*)(ab);                        /* rt0 ks0 */            \
        f16x8 a01 = *(const f16x8*)(ab + 32);                   /* rt0 ks1 */            \
        f16x8 a10 = *(const f16x8*)(ab + 32 * A_STRIDE);        /* rt1 ks0 */            \
        f16x8 a11 = *(const f16x8*)(ab + 32 * A_STRIDE + 32);   /* rt1 ks1 */            \
        __builtin_amdgcn_s_setprio(1);                                                   \
        acc[0][0] = MFMA32(a00, C0, acc[0][0]);                                          \
        acc[0][1] = MFMA32(a00, C2, acc[0][1]);                                          \
        acc[0][2] = MFMA32(a00, C4, acc[0][2]);                                          \
        acc[1][0] = MFMA32(a10, C0, acc[1][0]);                                          \
        acc[1][1] = MFMA32(a10, C2, acc[1][1]);                                          \
        acc[1][2] = MFMA32(a10, C4, acc[1][2]);                                          \
        acc[0][0] = MFMA32(a01, C1, acc[0][0]);                                          \
        acc[0][1] = MFMA32(a01, C3, acc[0][1]);                                          \
        acc[0][2] = MFMA32(a01, C5, acc[0][2]);                                          \
        acc[1][0] = MFMA32(a11, C1, acc[1][0]);                                          \
        acc[1][1] = MFMA32(a11, C3, acc[1][1]);                                          \
        acc[1][2] = MFMA32(a11, C5, acc[1][2]);                                          \
        __builtin_amdgcn_s_setprio(0);                                                   \
    }

    #pragma unroll 1
    for (int kc = 0; kc < NCHUNK; kc += 2) {
        CHUNK(kc,     pA0, pA1, pA2, pA3, pA4, pA5, pB0, pB1, pB2, pB3, pB4, pB5)
        CHUNK(kc + 1, pB0, pB1, pB2, pB3, pB4, pB5, pA0, pA1, pA2, pA3, pA4, pA5)
    }
#undef CHUNK

    // ---- epilogue: per-wave col-partial scores ----
    float pr[2][16];
    #pragma unroll
    for (int rt = 0; rt < 2; ++rt)
        #pragma unroll
        for (int reg = 0; reg < 16; ++reg) pr[rt][reg] = 0.f;

    #pragma unroll
    for (int ct = 0; ct < 3; ++ct) {
        int col = wave * 96 + ct * 32 + l31;
        float bj = bias_s[col];
        float vj = v_s[col];
        #pragma unroll
        for (int rt = 0; rt < 2; ++rt)
            #pragma unroll
            for (int reg = 0; reg < 16; ++reg)
                pr[rt][reg] = fmaf(vj, tanh_fast(acc[rt][ct][reg] + bj), pr[rt][reg]);
    }
    // reduce over the 32 cols (lanes l31; xor masks stay within each 32-lane half)
    #pragma unroll
    for (int rt = 0; rt < 2; ++rt)
        #pragma unroll
        for (int reg = 0; reg < 16; ++reg) {
            float x = pr[rt][reg];
            x += __shfl_xor(x, 1);
            x += __shfl_xor(x, 2);
            x += __shfl_xor(x, 4);
            x += __shfl_xor(x, 8);
            x += __shfl_xor(x, 16);
            if (l31 == 0) {   // lanes 0 and 32 write disjoint rows (4*lhi term)
                int rl = (reg & 3) + 8 * (reg >> 2) + 4 * lhi;
                s_red[wave * 64 + rt * 32 + rl] = x;
            }
        }
    __syncthreads();

    // rows: sum 8 col-group partials, exp, block Z
    if (tid < 64) {
        float s = 0.f;
        #pragma unroll
        for (int w = 0; w < 8; ++w) s += s_red[w * 64 + tid];
        float e = __expf(s);            // |s| <= ||v||_1 ~ 61: no overflow
        e_lds[tid] = e;
        float tot = e;
        tot += __shfl_xor(tot, 1);
        tot += __shfl_xor(tot, 2);
        tot += __shfl_xor(tot, 4);
        tot += __shfl_xor(tot, 8);
        tot += __shfl_xor(tot, 16);
        tot += __shfl_xor(tot, 32);
        if (tid == 0) atomicAdd(Z, tot);
    }
    __syncthreads();

    // ---- fused weighted sum from resident A (h read from HBM exactly once), f16x2/lane ----
    if (tid < 384) {
        float s0 = 0.f, s1 = 0.f;
        #pragma unroll 8
        for (int i = 0; i < BM; ++i) {
            f16x2 a2 = *(const f16x2*)(smem + LDS_A + i * A_STRIDE + tid * 4);
            float e = e_lds[i];
            s0 = fmaf(e, (float)a2[0], s0);
            s1 = fmaf(e, (float)a2[1], s1);
        }
        if (use_part) {
            float* dst = part + (size_t)blockIdx.x * HDIM + tid * 2;
            dst[0] = s0; dst[1] = s1;
        } else {
            atomicAdd(accbuf + tid * 2, s0);
            atomicAdd(accbuf + tid * 2 + 1, s1);
        }
    }
}

// ---------------- finalize stage 1: sum 2048 parts in 16 groups of 128 ----------------
__global__ __launch_bounds__(128) void fin1_kernel(
    const float* __restrict__ part, float* __restrict__ part2) {
    const int g  = blockIdx.x / 6;           // group 0..15
    const int cb = blockIdx.x % 6;
    const int col = cb * 128 + threadIdx.x;
    float s = 0.f;
    #pragma unroll 8
    for (int p = g * 128; p < (g + 1) * 128; ++p) s += part[(size_t)p * HDIM + col];
    part2[g * HDIM + col] = s;
}

// ---------------- finalize stage 2: out[j] = sum_g src[g][j] / Z ----------------
__global__ __launch_bounds__(128) void fin2_kernel(
    const float* __restrict__ src, const float* __restrict__ Z,
    float* __restrict__ out, int ngroups) {
    const int col = blockIdx.x * 128 + threadIdx.x;
    float s = 0.f;
    for (int g = 0; g < ngroups; ++g) s += src[g * HDIM + col];
    out[col] = s / (*Z);
}

extern "C" void kernel_launch(void* const* d_in, const int* in_sizes, int n_in,
                              void* d_out, int out_size, void* d_ws, size_t ws_size,
                              hipStream_t stream) {
    const float* h    = (const float*)d_in[0];   // [N, 768]
    const float* W    = (const float*)d_in[1];   // [768, 768]
    const float* bias = (const float*)d_in[2];   // [768]
    const float* vv   = (const float*)d_in[3];   // [1, 768]
    float* out = (float*)d_out;                  // [1, 768] fp32

    const int n = in_sizes[0] / HDIM;            // 131072

    char* ws = (char*)d_ws;
    _Float16* Wt  = (_Float16*)(ws + WS_WT);
    float* Z      = (float*)(ws + WS_Z);
    float* part   = (float*)(ws + WS_PART);
    float* part2  = (float*)(ws + WS_PART2);
    float* accbuf = (float*)(ws + WS_PART);      // small-ws fallback accumulator

    const int use_part = (ws_size >= (size_t)WS_NEED) ? 1 : 0;

    hipFuncSetAttribute((const void*)score_fused_kernel,
                        hipFuncAttributeMaxDynamicSharedMemorySize, LDS_TOTAL);

    // 1) W -> fp16 chunks; zero Z (+acc)
    prep_kernel<<<72, 1024, 0, stream>>>(W, Wt, Z, accbuf);

    // 2) fused score + exp + weighted-sum partials
    score_fused_kernel<<<n / BM, 512, LDS_TOTAL, stream>>>(
        h, Wt, bias, vv, part, accbuf, Z, use_part);

    // 3) reduce partials
    if (use_part) {
        fin1_kernel<<<96, 128, 0, stream>>>(part, part2);
        fin2_kernel<<<HDIM / 128, 128, 0, stream>>>(part2, Z, out, 16);
    } else {
        fin2_kernel<<<HDIM / 128, 128, 0, stream>>>(accbuf, Z, out, 1);
    }
}